// Round 1
// baseline (1482.796 us; speedup 1.0000x reference)
//
#include <hip/hip_runtime.h>
#include <hip/hip_bf16.h>

#define TT 8192
#define HD 1024
#define FD 4096
#define NE 8

typedef float f32x4 __attribute__((ext_vector_type(4)));
typedef short bf16x8 __attribute__((ext_vector_type(8)));

#define LDS_CAST(p) ((__attribute__((address_space(3))) void*)(p))
#define GLB_CAST(p) ((const __attribute__((address_space(1))) void*)(p))

static __device__ __forceinline__ int imin(int a, int b) { return a < b ? a : b; }

// ---------------- x fp32 -> bf16 ----------------
__global__ void cvt_x_kernel(const float* __restrict__ in, __hip_bfloat16* __restrict__ out) {
    size_t i = (size_t)blockIdx.x * blockDim.x + threadIdx.x;  // over TT*HD/8
    if (i >= (size_t)TT * HD / 8) return;
    const float4* p = (const float4*)(in + i * 8);
    float4 a = p[0], b = p[1];
    __hip_bfloat16 t8[8];
    t8[0] = __float2bfloat16(a.x); t8[1] = __float2bfloat16(a.y);
    t8[2] = __float2bfloat16(a.z); t8[3] = __float2bfloat16(a.w);
    t8[4] = __float2bfloat16(b.x); t8[5] = __float2bfloat16(b.y);
    t8[6] = __float2bfloat16(b.z); t8[7] = __float2bfloat16(b.w);
    *(uint4*)(out + i * 8) = *(const uint4*)t8;
}

// ---------- weight fp32 [R][C] -> bf16 [C][R] (per expert) ----------
__global__ void transpose_cvt_kernel(const float* __restrict__ in, __hip_bfloat16* __restrict__ out,
                                     int R, int C) {
    __shared__ __hip_bfloat16 tile[64][65];
    int e = blockIdx.z;
    in  += (size_t)e * R * C;
    out += (size_t)e * R * C;
    int c0 = blockIdx.x * 64, r0 = blockIdx.y * 64;
    int tx = threadIdx.x, ty = threadIdx.y;
    #pragma unroll
    for (int r = ty; r < 64; r += 4)
        tile[r][tx] = __float2bfloat16(in[(size_t)(r0 + r) * C + c0 + tx]);
    __syncthreads();
    #pragma unroll
    for (int r = ty; r < 64; r += 4)
        out[(size_t)(c0 + r) * R + r0 + tx] = tile[tx][r];
}

// ---------------- router: logits, softmax, top-2, lists, aux sums ----------------
__global__ void router_kernel(const float* __restrict__ x, const float* __restrict__ gw,
                              int* __restrict__ count, int* __restrict__ list,
                              float* __restrict__ wlist, float* __restrict__ sums) {
    __shared__ float wsum[4][9];
    int tid = threadIdx.x, lane = tid & 63, wid = tid >> 6;
    float lsum[9];
    #pragma unroll
    for (int i = 0; i < 9; ++i) lsum[i] = 0.f;
    int gwave = blockIdx.x * 4 + wid;
    for (int t = gwave; t < TT; t += 1024) {
        float acc[NE];
        #pragma unroll
        for (int e = 0; e < NE; ++e) acc[e] = 0.f;
        const float* xr = x + (size_t)t * HD;
        for (int i = 0; i < HD / 64; ++i) {
            int j = lane + 64 * i;
            float xv = xr[j];
            const float* g = gw + j * NE;
            #pragma unroll
            for (int e = 0; e < NE; ++e) acc[e] = fmaf(xv, g[e], acc[e]);
        }
        #pragma unroll
        for (int e = 0; e < NE; ++e) {
            float v = acc[e];
            #pragma unroll
            for (int off = 32; off > 0; off >>= 1) v += __shfl_xor(v, off);
            acc[e] = v;
        }
        float mx = acc[0];
        #pragma unroll
        for (int e = 1; e < NE; ++e) mx = fmaxf(mx, acc[e]);
        float p[NE]; float s = 0.f;
        #pragma unroll
        for (int e = 0; e < NE; ++e) { p[e] = __expf(acc[e] - mx); s += p[e]; }
        float inv_s = 1.f / s;
        float lse = mx + __logf(s);
        int i0 = 0; float v0 = acc[0];
        #pragma unroll
        for (int e = 1; e < NE; ++e) if (acc[e] > v0) { v0 = acc[e]; i0 = e; }
        int i1 = -1; float v1 = -3.4e38f;
        #pragma unroll
        for (int e = 0; e < NE; ++e) if (e != i0 && acc[e] > v1) { v1 = acc[e]; i1 = e; }
        if (lane == 0) {
            float pw = 1.f / (p[i0] + p[i1]);
            int pos0 = atomicAdd(&count[i0], 1);
            list[i0 * TT + pos0] = t; wlist[i0 * TT + pos0] = p[i0] * pw;
            int pos1 = atomicAdd(&count[i1], 1);
            list[i1 * TT + pos1] = t; wlist[i1 * TT + pos1] = p[i1] * pw;
            #pragma unroll
            for (int e = 0; e < NE; ++e) lsum[e] += p[e] * inv_s;
            lsum[8] += lse * lse;
        }
    }
    if (lane == 0) {
        #pragma unroll
        for (int i = 0; i < 9; ++i) wsum[wid][i] = lsum[i];
    }
    __syncthreads();
    if (tid < 9) {
        float v = wsum[0][tid] + wsum[1][tid] + wsum[2][tid] + wsum[3][tid];
        unsafeAtomicAdd(&sums[tid], v);
    }
}

// ---------------- prefix offsets + aux losses ----------------
__global__ void finalize_kernel(const int* __restrict__ count, int* __restrict__ offsets,
                                const float* __restrict__ sums, float* __restrict__ tail) {
    int o = 0; float bal = 0.f;
    for (int e = 0; e < NE; ++e) {
        offsets[e] = o; o += count[e];
        bal += ((float)count[e] / (float)(TT * 2)) * (sums[e] / (float)TT);
    }
    tail[0] = (float)NE * bal;
    tail[1] = sums[8] / (float)TT;
}

// ---------------- fused gate/up GEMM + SwiGLU -> h (bf16) ----------------
// A: gathered x rows [cnt][HD] bf16; B: wg/wu transposed [E][FD][HD] bf16.
__global__ __launch_bounds__(256, 2) void gemm_gateup_kernel(
    const __hip_bfloat16* __restrict__ xbf,
    const __hip_bfloat16* __restrict__ wg,
    const __hip_bfloat16* __restrict__ wu,
    const int* __restrict__ count, const int* __restrict__ offsets,
    const int* __restrict__ list,
    __hip_bfloat16* __restrict__ hbuf) {
    int e = blockIdx.z;
    int cnt = count[e];
    int bm0 = blockIdx.x * 128;
    if (bm0 >= cnt) return;
    int bn0 = blockIdx.y * 128;
    __shared__ __align__(16) __hip_bfloat16 sA[128 * 64];
    __shared__ __align__(16) __hip_bfloat16 sG[128 * 64];
    __shared__ __align__(16) __hip_bfloat16 sU[128 * 64];
    int tid = threadIdx.x, lane = tid & 63, wid = tid >> 6;
    int wr = (wid >> 1) * 64, wc = (wid & 1) * 64;

    const __hip_bfloat16* ap[4];
    const __hip_bfloat16* gp[4];
    const __hip_bfloat16* up[4];
    unsigned ldsb[4];
    #pragma unroll
    for (int it = 0; it < 4; ++it) {
        int c = it * 256 + tid;
        int row = c >> 3;
        int col8 = (c & 7) ^ (row & 7);          // pre-swizzled source (rule 21)
        int grow = bm0 + row;
        int trow = list[e * TT + imin(grow, cnt - 1)];
        ap[it] = xbf + (size_t)trow * HD + col8 * 8;
        int gn = bn0 + row;
        gp[it] = wg + ((size_t)e * FD + gn) * HD + col8 * 8;
        up[it] = wu + ((size_t)e * FD + gn) * HD + col8 * 8;
        ldsb[it] = (unsigned)((it * 256 + wid * 64) * 16);
    }

    f32x4 zero = {0.f, 0.f, 0.f, 0.f};
    f32x4 accg[4][4], accu[4][4];
    #pragma unroll
    for (int m = 0; m < 4; ++m)
        #pragma unroll
        for (int n = 0; n < 4; ++n) { accg[m][n] = zero; accu[m][n] = zero; }

    for (int kt = 0; kt < HD / 64; ++kt) {
        #pragma unroll
        for (int it = 0; it < 4; ++it) {
            __builtin_amdgcn_global_load_lds(GLB_CAST(ap[it]), LDS_CAST((char*)sA + ldsb[it]), 16, 0, 0);
            __builtin_amdgcn_global_load_lds(GLB_CAST(gp[it]), LDS_CAST((char*)sG + ldsb[it]), 16, 0, 0);
            __builtin_amdgcn_global_load_lds(GLB_CAST(up[it]), LDS_CAST((char*)sU + ldsb[it]), 16, 0, 0);
            ap[it] += 64; gp[it] += 64; up[it] += 64;
        }
        __syncthreads();
        #pragma unroll
        for (int ks = 0; ks < 2; ++ks) {
            int kb = ks * 64 + (lane >> 4) * 16;
            bf16x8 af[4], bg[4], bu[4];
            #pragma unroll
            for (int m = 0; m < 4; ++m) {
                int r = wr + m * 16 + (lane & 15);
                int byt = (r * 128 + kb) ^ ((r & 7) << 4);
                af[m] = *(const bf16x8*)((const char*)sA + byt);
            }
            #pragma unroll
            for (int n = 0; n < 4; ++n) {
                int r = wc + n * 16 + (lane & 15);
                int byt = (r * 128 + kb) ^ ((r & 7) << 4);
                bg[n] = *(const bf16x8*)((const char*)sG + byt);
                bu[n] = *(const bf16x8*)((const char*)sU + byt);
            }
            #pragma unroll
            for (int m = 0; m < 4; ++m)
                #pragma unroll
                for (int n = 0; n < 4; ++n) {
                    accg[m][n] = __builtin_amdgcn_mfma_f32_16x16x32_bf16(af[m], bg[n], accg[m][n], 0, 0, 0);
                    accu[m][n] = __builtin_amdgcn_mfma_f32_16x16x32_bf16(af[m], bu[n], accu[m][n], 0, 0, 0);
                }
        }
        __syncthreads();
    }
    int hbase = offsets[e];
    #pragma unroll
    for (int m = 0; m < 4; ++m) {
        #pragma unroll
        for (int r = 0; r < 4; ++r) {
            int rl = wr + m * 16 + (lane >> 4) * 4 + r;
            int grow = bm0 + rl;
            if (grow >= cnt) continue;
            size_t ro = (size_t)(hbase + grow) * FD + bn0;
            #pragma unroll
            for (int n = 0; n < 4; ++n) {
                int col = wc + n * 16 + (lane & 15);
                float g = accg[m][n][r];
                float u = accu[m][n][r];
                float hv = g * u / (1.f + __expf(-g));
                hbuf[ro + col] = __float2bfloat16(hv);
            }
        }
    }
}

// ---------------- down GEMM + weighted scatter-add into out ----------------
// A: h [rows][FD] bf16; B: wd transposed [E][HD][FD] bf16.
__global__ __launch_bounds__(256, 2) void gemm_down_kernel(
    const __hip_bfloat16* __restrict__ hbuf,
    const __hip_bfloat16* __restrict__ wd,
    const int* __restrict__ count, const int* __restrict__ offsets,
    const int* __restrict__ list, const float* __restrict__ wlist,
    float* __restrict__ out) {
    int e = blockIdx.z;
    int cnt = count[e];
    int bm0 = blockIdx.x * 128;
    if (bm0 >= cnt) return;
    int bn0 = blockIdx.y * 128;
    __shared__ __align__(16) __hip_bfloat16 sA[128 * 64];
    __shared__ __align__(16) __hip_bfloat16 sB[128 * 64];
    int tid = threadIdx.x, lane = tid & 63, wid = tid >> 6;
    int wr = (wid >> 1) * 64, wc = (wid & 1) * 64;
    int hbase = offsets[e];

    const __hip_bfloat16* ap[4];
    const __hip_bfloat16* bp[4];
    unsigned ldsb[4];
    #pragma unroll
    for (int it = 0; it < 4; ++it) {
        int c = it * 256 + tid;
        int row = c >> 3;
        int col8 = (c & 7) ^ (row & 7);
        int grow = bm0 + row;
        int hrow = hbase + imin(grow, cnt - 1);
        ap[it] = hbuf + (size_t)hrow * FD + col8 * 8;
        int gn = bn0 + row;
        bp[it] = wd + ((size_t)e * HD + gn) * FD + col8 * 8;
        ldsb[it] = (unsigned)((it * 256 + wid * 64) * 16);
    }

    f32x4 zero = {0.f, 0.f, 0.f, 0.f};
    f32x4 acc[4][4];
    #pragma unroll
    for (int m = 0; m < 4; ++m)
        #pragma unroll
        for (int n = 0; n < 4; ++n) acc[m][n] = zero;

    for (int kt = 0; kt < FD / 64; ++kt) {
        #pragma unroll
        for (int it = 0; it < 4; ++it) {
            __builtin_amdgcn_global_load_lds(GLB_CAST(ap[it]), LDS_CAST((char*)sA + ldsb[it]), 16, 0, 0);
            __builtin_amdgcn_global_load_lds(GLB_CAST(bp[it]), LDS_CAST((char*)sB + ldsb[it]), 16, 0, 0);
            ap[it] += 64; bp[it] += 64;
        }
        __syncthreads();
        #pragma unroll
        for (int ks = 0; ks < 2; ++ks) {
            int kb = ks * 64 + (lane >> 4) * 16;
            bf16x8 af[4], bf[4];
            #pragma unroll
            for (int m = 0; m < 4; ++m) {
                int r = wr + m * 16 + (lane & 15);
                int byt = (r * 128 + kb) ^ ((r & 7) << 4);
                af[m] = *(const bf16x8*)((const char*)sA + byt);
            }
            #pragma unroll
            for (int n = 0; n < 4; ++n) {
                int r = wc + n * 16 + (lane & 15);
                int byt = (r * 128 + kb) ^ ((r & 7) << 4);
                bf[n] = *(const bf16x8*)((const char*)sB + byt);
            }
            #pragma unroll
            for (int m = 0; m < 4; ++m)
                #pragma unroll
                for (int n = 0; n < 4; ++n)
                    acc[m][n] = __builtin_amdgcn_mfma_f32_16x16x32_bf16(af[m], bf[n], acc[m][n], 0, 0, 0);
        }
        __syncthreads();
    }
    #pragma unroll
    for (int m = 0; m < 4; ++m) {
        #pragma unroll
        for (int r = 0; r < 4; ++r) {
            int rl = wr + m * 16 + (lane >> 4) * 4 + r;
            int grow = bm0 + rl;
            if (grow >= cnt) continue;
            int t = list[e * TT + grow];
            float w = wlist[e * TT + grow];
            #pragma unroll
            for (int n = 0; n < 4; ++n) {
                int col = bn0 + wc + n * 16 + (lane & 15);
                unsafeAtomicAdd(&out[(size_t)t * HD + col], w * acc[m][n][r]);
            }
        }
    }
}

extern "C" void kernel_launch(void* const* d_in, const int* in_sizes, int n_in,
                              void* d_out, int out_size, void* d_ws, size_t ws_size,
                              hipStream_t stream) {
    const float* x  = (const float*)d_in[0];
    const float* gw = (const float*)d_in[1];
    const float* wg = (const float*)d_in[2];
    const float* wu = (const float*)d_in[3];
    const float* wd = (const float*)d_in[4];
    float* out = (float*)d_out;

    char* ws = (char*)d_ws;
    int*   cntp  = (int*)(ws + 0);        // 8 ints
    float* sums  = (float*)(ws + 64);     // 9 floats
    int*   offs  = (int*)(ws + 128);      // 8 ints
    int*   list  = (int*)(ws + 256);                       // 8*8192 ints
    float* wlist = (float*)(ws + 262400);                  // 8*8192 floats
    __hip_bfloat16* xbf  = (__hip_bfloat16*)(ws + 524544);          // 8192*1024
    __hip_bfloat16* wgbf = xbf + (size_t)TT * HD;                   // 8*4096*1024 (transposed)
    __hip_bfloat16* wubf = wgbf + (size_t)NE * FD * HD;
    __hip_bfloat16* wdbf = wubf + (size_t)NE * FD * HD;             // 8*1024*4096 (transposed)
    __hip_bfloat16* hbuf = wdbf + (size_t)NE * HD * FD;             // 16384*4096

    hipMemsetAsync(ws, 0, 256, stream);
    hipMemsetAsync(d_out, 0, (size_t)out_size * sizeof(float), stream);

    cvt_x_kernel<<<4096, 256, 0, stream>>>(x, xbf);
    transpose_cvt_kernel<<<dim3(FD / 64, HD / 64, NE), dim3(64, 4), 0, stream>>>(wg, wgbf, HD, FD);
    transpose_cvt_kernel<<<dim3(FD / 64, HD / 64, NE), dim3(64, 4), 0, stream>>>(wu, wubf, HD, FD);
    transpose_cvt_kernel<<<dim3(HD / 64, FD / 64, NE), dim3(64, 4), 0, stream>>>(wd, wdbf, FD, HD);
    router_kernel<<<256, 256, 0, stream>>>(x, gw, cntp, list, wlist, sums);
    finalize_kernel<<<1, 1, 0, stream>>>(cntp, offs, sums, out + (size_t)TT * HD);
    gemm_gateup_kernel<<<dim3(TT / 128, FD / 128, NE), 256, 0, stream>>>(xbf, wgbf, wubf, cntp, offs, list, hbuf);
    gemm_down_kernel<<<dim3(TT / 128, HD / 128, NE), 256, 0, stream>>>(hbuf, wdbf, cntp, offs, list, wlist, out);
}